// Round 15
// baseline (749.212 us; speedup 1.0000x reference)
//
#include <hip/hip_runtime.h>
#include <stdint.h>

#define GM 4096   // 2*2048 rows of x
#define GN 8192   // out_features
#define GK 2048   // in_features

typedef float f32x4 __attribute__((ext_vector_type(4)));
typedef int i32x4 __attribute__((ext_vector_type(4)));

// round(NF4[i]*127)
__device__ __constant__ int LUT8[16] = {
    -127, -88, -67, -50, -36, -23, -12, 0, 10, 20, 31, 43, 56, 71, 92, 127};

// ---- Pass 1 (merged): x -> per-row int8 (+ row scale)  AND  NF4 -> int8 W ----
// blocks [0,4096): one block per x row (2048 f32): absmax reduce + quantize.
// blocks [4096,12288): W codes -> i8 via LUT, 8 codes/thread.
__global__ void __launch_bounds__(256) prep_i8_kernel(
    const int* __restrict__ q, const float* __restrict__ x,
    signed char* __restrict__ wq, signed char* __restrict__ xq,
    float* __restrict__ xr) {
  __shared__ float red[256];
  int b = blockIdx.x;
  int tid = threadIdx.x;
  if (b < 4096) {
    const float4* xrow = reinterpret_cast<const float4*>(x + (size_t)b * GK);
    float4 v0 = xrow[2 * tid];
    float4 v1 = xrow[2 * tid + 1];
    float m8 = fmaxf(fmaxf(fmaxf(fabsf(v0.x), fabsf(v0.y)),
                           fmaxf(fabsf(v0.z), fabsf(v0.w))),
                     fmaxf(fmaxf(fabsf(v1.x), fabsf(v1.y)),
                           fmaxf(fabsf(v1.z), fabsf(v1.w))));
    red[tid] = m8;
    __syncthreads();
    for (int s = 128; s > 0; s >>= 1) {
      if (tid < s) red[tid] = fmaxf(red[tid], red[tid + s]);
      __syncthreads();
    }
    float mx = fmaxf(red[0], 1e-20f);
    float qs = 127.0f / mx;
    float vals[8] = {v0.x, v0.y, v0.z, v0.w, v1.x, v1.y, v1.z, v1.w};
    unsigned int lo = 0, hi = 0;
#pragma unroll
    for (int j = 0; j < 4; ++j) {
      int t = __float2int_rn(vals[j] * qs);
      lo |= ((unsigned int)(t & 0xff)) << (8 * j);
    }
#pragma unroll
    for (int j = 0; j < 4; ++j) {
      int t = __float2int_rn(vals[4 + j] * qs);
      hi |= ((unsigned int)(t & 0xff)) << (8 * j);
    }
    uint2 pv; pv.x = lo; pv.y = hi;
    reinterpret_cast<uint2*>(xq)[(size_t)b * 256 + tid] = pv;
    if (tid == 0) xr[b] = mx * (1.0f / 16129.0f);  // xmax/127^2
  } else {
    size_t t = (size_t)(b - 4096) * 256 + tid;
    const int4* q4 = reinterpret_cast<const int4*>(q);
    int4 c0 = q4[2 * t];
    int4 c1 = q4[2 * t + 1];
    int codes[8] = {c0.x, c0.y, c0.z, c0.w, c1.x, c1.y, c1.z, c1.w};
    unsigned int lo = 0, hi = 0;
#pragma unroll
    for (int j = 0; j < 4; ++j)
      lo |= ((unsigned int)(LUT8[codes[j] & 15] & 0xff)) << (8 * j);
#pragma unroll
    for (int j = 0; j < 4; ++j)
      hi |= ((unsigned int)(LUT8[codes[4 + j] & 15] & 0xff)) << (8 * j);
    uint2 pv; pv.x = lo; pv.y = hi;
    reinterpret_cast<uint2*>(wq)[t] = pv;
  }
}

// ------ Pass 2: persistent 256x256 int8 GEMM (R10 skeleton, i8 payload) ----
// 8 waves (2Mx4N), BK=64 = one NF4 scale block = one mfma_i32_16x16x64_i8.
// Per tile: 8 i8 MFMA/wave/quadrant-phase... (4mi x 2ni per quadrant), with
// in-loop rescale acc_f32 += (f32)dot_i32 * scale[n][kb]; row factor
// xmax[m]/127^2 applied at flush. Stages are 1 instr/half (8KB) -> VM3
// replaces VM6 (ledger re-derived; binding: B1@P1 read at P6 = 4th newest
// at P4 check). B-scales prefetched one tile ahead at P1/P5 (4 dwords,
// drained by the same VM3). LDS 2x32KB. Swizzle g ^ ((row>>1)&3) for 64B
// rows (measured 0 conflicts in R6/R12). Persistent 2 tiles, XCD-affine.
#define AS1(p) ((const __attribute__((address_space(1))) void*)(p))
#define AS3(p) ((__attribute__((address_space(3))) void*)(p))
#define VM3() asm volatile("s_waitcnt vmcnt(3)" ::: "memory")
#define FENCE() asm volatile("" ::: "memory")
#define BAR() do { FENCE(); __builtin_amdgcn_s_barrier(); FENCE(); } while (0)

__global__ void __launch_bounds__(512, 1) gemm_i8_kernel(
    const signed char* __restrict__ A,   // xq [GM][GK]
    const signed char* __restrict__ B,   // wq [GN][GK]
    const float* __restrict__ scale,     // [GN*32] per-64-block
    const float* __restrict__ xr,        // [GM] xmax/127^2
    const float* __restrict__ bias, float* __restrict__ C) {
  constexpr int BK = 64;
  constexpr int NV = 64;  // 2 output tiles x 32 K-tiles
  __shared__ __align__(16) signed char As[2 * 256 * 64];  // 32 KB
  __shared__ __align__(16) signed char Bs[2 * 256 * 64];  // 32 KB

  int bid = blockIdx.x;                    // nwg = 256, %8==0 -> bijective
  int swz = (bid & 7) * 32 + (bid >> 3);
  int brow = (swz & 15) * 256;
  int pair = swz >> 4;
  int bcol0 = pair * 512;

  int tid = threadIdx.x;
  int lane = tid & 63;
  int wave = tid >> 6;
  int wr = wave >> 2;   // 0..1
  int wc = wave & 3;    // 0..3
  int fr = lane & 15;
  int slot = lane >> 4;

  const signed char* Abase = A + (size_t)brow * GK;
  const signed char* Bbase0 = B + (size_t)bcol0 * GK;
  const signed char* Bbase1 = Bbase0 + (size_t)256 * GK;

  f32x4 acc[8][4] = {};
  i32x4 a0[2][4], a1[2][4], b0[2][2], b1[2][2];
  float sc[2][4];

  auto ldfrag = [&](const signed char* lds, int buf, int half,
                    int r) -> i32x4 {
    int off = buf * 16384 + half * 8192 + r * 64 +
              ((slot ^ ((r >> 1) & 3)) << 4);
    return *reinterpret_cast<const i32x4*>(lds + off);
  };
  // one call stages one half-tile (128 rows x 64 i8 = 8KB = 512 x 16B)
  auto stage = [&](const signed char* gtile, signed char* lds, int buf,
                   int h, int kt) {
    int r = tid >> 2;
    int gp = (tid & 3) ^ ((r >> 1) & 3);
    __builtin_amdgcn_global_load_lds(
        AS1(gtile + (size_t)(h * 128 + r) * GK + kt + gp * 16),
        AS3(lds + buf * 16384 + h * 8192 + tid * 16), 16, 0, 0);
  };
  auto RD_A0 = [&](int p) {
#pragma unroll
    for (int m = 0; m < 4; ++m)
      a0[p][m] = ldfrag(As, p, 0, wr * 64 + m * 16 + fr);
  };
  auto RD_A1 = [&](int p) {
#pragma unroll
    for (int m = 0; m < 4; ++m)
      a1[p][m] = ldfrag(As, p, 1, wr * 64 + m * 16 + fr);
  };
  auto RD_B0 = [&](int p) {
#pragma unroll
    for (int n = 0; n < 2; ++n)
      b0[p][n] = ldfrag(Bs, p, 0, wc * 32 + n * 16 + fr);
  };
  auto RD_B1 = [&](int p) {
#pragma unroll
    for (int n = 0; n < 2; ++n)
      b1[p][n] = ldfrag(Bs, p, 1, wc * 32 + n * 16 + fr);
  };
  // load scales for tile t (4 ni cols) into parity p
  auto LD_SC = [&](int p, int t, int bc) {
    int kb = t & 31;
#pragma unroll
    for (int ni = 0; ni < 4; ++ni) {
      int col = bc + (ni >> 1) * 128 + wc * 32 + (ni & 1) * 16 + fr;
      sc[p][ni] = scale[(size_t)col * 32 + kb];
    }
  };
  i32x4 zero = {0, 0, 0, 0};
  auto Q1 = [&](int p) {  // a0 x b0 -> acc[0..3][0..1]
    __builtin_amdgcn_s_setprio(1);
#pragma unroll
    for (int m = 0; m < 4; ++m)
#pragma unroll
      for (int n = 0; n < 2; ++n) {
        i32x4 d = __builtin_amdgcn_mfma_i32_16x16x64_i8(
            a0[p][m], b0[p][n], zero, 0, 0, 0);
#pragma unroll
        for (int r = 0; r < 4; ++r)
          acc[m][n][r] = fmaf((float)d[r], sc[p][n], acc[m][n][r]);
      }
    __builtin_amdgcn_s_setprio(0);
  };
  auto Q2 = [&](int p) {  // a1 x b0 -> acc[4..7][0..1]
    __builtin_amdgcn_s_setprio(1);
#pragma unroll
    for (int m = 0; m < 4; ++m)
#pragma unroll
      for (int n = 0; n < 2; ++n) {
        i32x4 d = __builtin_amdgcn_mfma_i32_16x16x64_i8(
            a1[p][m], b0[p][n], zero, 0, 0, 0);
#pragma unroll
        for (int r = 0; r < 4; ++r)
          acc[4 + m][n][r] = fmaf((float)d[r], sc[p][n], acc[4 + m][n][r]);
      }
    __builtin_amdgcn_s_setprio(0);
  };
  auto Q3 = [&](int p) {  // a1 x b1 -> acc[4..7][2..3]
    __builtin_amdgcn_s_setprio(1);
#pragma unroll
    for (int m = 0; m < 4; ++m)
#pragma unroll
      for (int n = 0; n < 2; ++n) {
        i32x4 d = __builtin_amdgcn_mfma_i32_16x16x64_i8(
            a1[p][m], b1[p][n], zero, 0, 0, 0);
#pragma unroll
        for (int r = 0; r < 4; ++r)
          acc[4 + m][2 + n][r] =
              fmaf((float)d[r], sc[p][2 + n], acc[4 + m][2 + n][r]);
      }
    __builtin_amdgcn_s_setprio(0);
  };
  auto Q4 = [&](int p) {  // a0 x b1 -> acc[0..3][2..3]
    __builtin_amdgcn_s_setprio(1);
#pragma unroll
    for (int m = 0; m < 4; ++m)
#pragma unroll
      for (int n = 0; n < 2; ++n) {
        i32x4 d = __builtin_amdgcn_mfma_i32_16x16x64_i8(
            a0[p][m], b1[p][n], zero, 0, 0, 0);
#pragma unroll
        for (int r = 0; r < 4; ++r)
          acc[m][2 + n][r] = fmaf((float)d[r], sc[p][2 + n], acc[m][2 + n][r]);
      }
    __builtin_amdgcn_s_setprio(0);
  };
  auto flush = [&](int bc) {
    float bv[4];
#pragma unroll
    for (int n = 0; n < 4; ++n)
      bv[n] = bias[bc + (n >> 1) * 128 + wc * 32 + (n & 1) * 16 + fr];
#pragma unroll
    for (int m = 0; m < 8; ++m) {
      int grow0 = brow + (m >> 2) * 128 + wr * 64 + (m & 3) * 16 + slot * 4;
#pragma unroll
      for (int n = 0; n < 4; ++n) {
        int gcol = bc + (n >> 1) * 128 + wc * 32 + (n & 1) * 16 + fr;
#pragma unroll
        for (int r = 0; r < 4; ++r)
          C[(size_t)(grow0 + r) * GN + gcol] =
              acc[m][n][r] * xr[grow0 + r] + bv[n];
      }
    }
  };
  auto iter = [&](int j) {
    int t1 = 2 * j + 1;
    int t2 = 2 * j + 2; if (t2 > NV - 1) t2 = NV - 1;  // tail dummy restage
    int t3 = 2 * j + 3; if (t3 > NV - 1) t3 = NV - 1;
    const signed char* B1p = (t1 < 32) ? Bbase0 : Bbase1;
    const signed char* B2p = (t2 < 32) ? Bbase0 : Bbase1;
    const signed char* B3p = (t3 < 32) ? Bbase0 : Bbase1;
    int kt1 = (t1 & 31) * BK, kt2 = (t2 & 31) * BK, kt3 = (t3 & 31) * BK;
    // P1
    RD_A1(0);
    LD_SC(1, t1, (t1 < 32) ? bcol0 : bcol0 + 256);
    stage(B1p, Bs, 1, 1, kt1);
    BAR();
    Q1(0);
    // P2
    RD_B1(0);
    BAR();
    Q2(0);
    // P3
    stage(Abase, As, 0, 0, kt2);
    stage(B2p, Bs, 0, 0, kt2);
    BAR();
    Q3(0);
    // P4
    stage(Abase, As, 0, 1, kt2);
    VM3();
    BAR();
    RD_A0(1); RD_B0(1);
    Q4(0);
    // P5
    RD_A1(1);
    LD_SC(0, t2, (t2 < 32) ? bcol0 : bcol0 + 256);
    stage(B2p, Bs, 0, 1, kt2);
    BAR();
    Q1(1);
    // P6
    RD_B1(1);
    BAR();
    Q2(1);
    // P7
    stage(Abase, As, 1, 0, kt3);
    stage(B3p, Bs, 1, 0, kt3);
    BAR();
    Q3(1);
    // P8
    stage(Abase, As, 1, 1, kt3);
    VM3();
    BAR();
    RD_A0(0); RD_B0(0);
    Q4(1);
  };

  // Prologue: scales(t0) + stage t0 fully + t1 {A0,B0,A1}; VM3 -> t0 landed
  LD_SC(0, 0, bcol0);
  stage(Abase, As, 0, 0, 0);
  stage(Bbase0, Bs, 0, 0, 0);
  stage(Abase, As, 0, 1, 0);
  stage(Bbase0, Bs, 0, 1, 0);
  stage(Abase, As, 1, 0, BK);
  stage(Bbase0, Bs, 1, 0, BK);
  stage(Abase, As, 1, 1, BK);
  VM3();
  BAR();
  RD_A0(0); RD_B0(0);

#pragma unroll 1
  for (int j = 0; j < 16; ++j) iter(j);

  flush(bcol0);  // stores drain under the 2nd K-loop
#pragma unroll
  for (int m = 0; m < 8; ++m)
#pragma unroll
    for (int n = 0; n < 4; ++n)
      acc[m][n] = f32x4{0.f, 0.f, 0.f, 0.f};

#pragma unroll 1
  for (int j = 16; j < 32; ++j) iter(j);

  flush(bcol0 + 256);
}

__device__ __constant__ float NF4_LUT[16] = {
    -1.0f, -0.6961928009986877f, -0.5250730514526367f, -0.39491748809814453f,
    -0.28444138169288635f, -0.18477343022823334f, -0.09105003625154495f, 0.0f,
    0.07958029955625534f, 0.16093020141124725f, 0.24611230194568634f,
    0.33791524171829224f, 0.44070982933044434f, 0.5626170039176941f,
    0.7229568362236023f, 1.0f};

// ---------------- Fallback (ws too small): fp32, correct, slow ----------------
__global__ void __launch_bounds__(256) fallback_kernel(
    const float* __restrict__ x, const int* __restrict__ q,
    const float* __restrict__ scale, const float* __restrict__ bias,
    float* __restrict__ out) {
  __shared__ float wrow[GK];
  int n = blockIdx.x;
  for (int k = threadIdx.x; k < GK; k += 256) {
    size_t idx = (size_t)n * GK + k;
    wrow[k] = NF4_LUT[q[idx] & 15] * scale[idx >> 6];
  }
  __syncthreads();
  int m = blockIdx.y * 256 + threadIdx.x;
  const float* xr = x + (size_t)m * GK;
  float acc = 0.f;
  for (int k = 0; k < GK; ++k) acc += xr[k] * wrow[k];
  out[(size_t)m * GN + n] = acc + bias[n];
}

extern "C" void kernel_launch(void* const* d_in, const int* in_sizes, int n_in,
                              void* d_out, int out_size, void* d_ws, size_t ws_size,
                              hipStream_t stream) {
  const float* x = (const float*)d_in[0];
  const int* q = (const int*)d_in[1];
  const float* scale = (const float*)d_in[2];
  const float* bias = (const float*)d_in[3];
  float* out = (float*)d_out;

  const size_t wqb = (size_t)GN * GK;       // 16,777,216
  const size_t xqb = (size_t)GM * GK;       //  8,388,608
  const size_t xrb = (size_t)GM * 4;        //     16,384

  if (ws_size >= wqb + xqb + xrb) {
    signed char* wq = (signed char*)d_ws;
    signed char* xq = wq + wqb;
    float* xr = (float*)(xq + xqb);
    prep_i8_kernel<<<dim3(4096 + 8192), 256, 0, stream>>>(q, x, wq, xq, xr);
    gemm_i8_kernel<<<dim3(256), 512, 0, stream>>>(xq, wq, scale, xr, bias, out);
  } else {
    fallback_kernel<<<dim3(GN, GM / 256), 256, 0, stream>>>(x, q, scale, bias, out);
  }
}

// Round 16
// 150.966 us; speedup vs baseline: 4.9628x; 4.9628x over previous
//
#include <hip/hip_runtime.h>
#include <stdint.h>

#define GM 4096   // 2*2048 rows of x
#define GN 8192   // out_features
#define GK 2048   // in_features

typedef float f32x4 __attribute__((ext_vector_type(4)));
typedef __bf16 bf16x8 __attribute__((ext_vector_type(8)));

__device__ __constant__ float NF4_LUT[16] = {
    -1.0f, -0.6961928009986877f, -0.5250730514526367f, -0.39491748809814453f,
    -0.28444138169288635f, -0.18477343022823334f, -0.09105003625154495f, 0.0f,
    0.07958029955625534f, 0.16093020141124725f, 0.24611230194568634f,
    0.33791524171829224f, 0.44070982933044434f, 0.5626170039176941f,
    0.7229568362236023f, 1.0f};

__device__ __forceinline__ unsigned short f32_to_bf16_rne(float f) {
  union { float f; uint32_t u; } v;
  v.f = f;
  uint32_t lsb = (v.u >> 16) & 1u;
  v.u += 0x7fffu + lsb;
  return (unsigned short)(v.u >> 16);
}

// ---- Pass 1 (merged): NF4 dequant -> bf16 W  AND  x fp32 -> bf16 ----
// W: GN*GK/8 threads = 8192 blocks. x: GM*GK/8 threads = 4096 blocks.
__global__ void __launch_bounds__(256) prep_kernel(
    const int* __restrict__ q, const float* __restrict__ scale,
    unsigned short* __restrict__ w, const float* __restrict__ x,
    unsigned short* __restrict__ xb) {
  int b = blockIdx.x;
  if (b < 8192) {
    __shared__ float lut[16];
    if (threadIdx.x < 16) lut[threadIdx.x] = NF4_LUT[threadIdx.x];
    __syncthreads();
    int t = b * 256 + threadIdx.x;
    const int4* q4 = reinterpret_cast<const int4*>(q);
    int4 c0 = q4[2 * t];
    int4 c1 = q4[2 * t + 1];
    float s = scale[t >> 3];
    int codes[8] = {c0.x, c0.y, c0.z, c0.w, c1.x, c1.y, c1.z, c1.w};
    union { unsigned short u[8]; int4 v; } r;
#pragma unroll
    for (int j = 0; j < 8; ++j)
      r.u[j] = f32_to_bf16_rne(lut[codes[j] & 15] * s);
    reinterpret_cast<int4*>(w)[t] = r.v;
  } else {
    int t = (b - 8192) * 256 + threadIdx.x;
    const float4* x4 = reinterpret_cast<const float4*>(x);
    float4 a = x4[2 * t];
    float4 bb = x4[2 * t + 1];
    union { unsigned short u[8]; int4 v; } r;
    r.u[0] = f32_to_bf16_rne(a.x);  r.u[1] = f32_to_bf16_rne(a.y);
    r.u[2] = f32_to_bf16_rne(a.z);  r.u[3] = f32_to_bf16_rne(a.w);
    r.u[4] = f32_to_bf16_rne(bb.x); r.u[5] = f32_to_bf16_rne(bb.y);
    r.u[6] = f32_to_bf16_rne(bb.z); r.u[7] = f32_to_bf16_rne(bb.w);
    reinterpret_cast<int4*>(xb)[t] = r.v;
  }
}

// ------ Pass 2: persistent 256x256 GEMM (best-measured variant) ------
// 8 waves (2Mx4N), BK=64, 16x16x32 MFMA, LDS 2x64KB static parity bufs.
// Snake quadrants with read-ahead groups; stages P1:B1(O), P3:A0+B0(E+2),
// P4:A1(E+2), P5:B1(E+2), P7:A0+B0(O+2), P8:A1(O+2); vmcnt(6) at P4/P8.
// T2 swizzle byte ^= ((row&7)<<4) via pre-swizzled global src (0 conflicts).
// Persistent: 2 output tiles/block, XCD-affine B pair-panels (FETCH ~156MB),
// tile-1 flush drains under tile-2's K-loop.
// Converged plateau: ~134.5us GEMM, MfmaUtil 45%, ~1020 TF. Key constraint
// (verified R11/R12/R15): acc must stay MFMA-only (AGPR); arch VGPR budget
// at 2 waves/SIMD caps any deeper register pipeline or VALU-coupled acc.
#define AS1(p) ((const __attribute__((address_space(1))) void*)(p))
#define AS3(p) ((__attribute__((address_space(3))) void*)(p))
#define VM6() asm volatile("s_waitcnt vmcnt(6)" ::: "memory")
#define FENCE() asm volatile("" ::: "memory")
#define BAR() do { FENCE(); __builtin_amdgcn_s_barrier(); FENCE(); } while (0)

__global__ void __launch_bounds__(512, 1) gemm_8phase_kernel(
    const unsigned short* __restrict__ A,  // [GM][GK] bf16 bits
    const unsigned short* __restrict__ B,  // [GN][GK] bf16 bits
    const float* __restrict__ bias, float* __restrict__ C) {
  constexpr int BK = 64;
  constexpr int NV = 64;  // virtual K-tiles: 2 output tiles x 32
  __shared__ __align__(16) unsigned short As[2 * 256 * 64];  // 64 KB
  __shared__ __align__(16) unsigned short Bs[2 * 256 * 64];  // 64 KB

  int bid = blockIdx.x;                    // nwg = 256, %8==0 -> bijective
  int swz = (bid & 7) * 32 + (bid >> 3);
  int brow = (swz & 15) * 256;             // A panel varies within XCD
  int pair = swz >> 4;                     // B pair-panel is XCD-affine
  int bcol0 = pair * 512;

  int tid = threadIdx.x;
  int lane = tid & 63;
  int wave = tid >> 6;
  int wr = wave >> 2;   // 0..1
  int wc = wave & 3;    // 0..3
  int fr = lane & 15;
  int slot = lane >> 4;
  int swc = (slot << 4) ^ ((fr & 7) << 4);

  const unsigned short* Abase = A + (size_t)brow * GK;
  const unsigned short* Bbase0 = B + (size_t)bcol0 * GK;
  const unsigned short* Bbase1 = Bbase0 + (size_t)256 * GK;

  int arow = (wr * 64 + fr) * 128;
  int brw = (wc * 32 + fr) * 128;

  f32x4 acc[8][4] = {};
  bf16x8 a0[2][4][2], a1[2][4][2], b0[2][2][2], b1[2][2][2];

  auto ldA = [&](int buf, int qm, int m, int kk) -> bf16x8 {
    int off = buf * 32768 + qm * 16384 + m * 2048 + arow + (swc ^ (kk << 6));
    return *reinterpret_cast<const bf16x8*>((const char*)As + off);
  };
  auto ldB = [&](int buf, int qn, int n, int kk) -> bf16x8 {
    int off = buf * 32768 + qn * 16384 + n * 2048 + brw + (swc ^ (kk << 6));
    return *reinterpret_cast<const bf16x8*>((const char*)Bs + off);
  };
  auto stage = [&](const unsigned short* gtile, unsigned short* lds, int buf,
                   int h, int kt) {
#pragma unroll
    for (int i = 0; i < 2; ++i) {
      int L = h * 16384 + i * 8192 + tid * 16;
      int s = L ^ (((L >> 7) & 7) << 4);
      __builtin_amdgcn_global_load_lds(
          AS1(gtile + (size_t)(s >> 7) * GK + kt + ((s & 127) >> 1)),
          AS3((char*)lds + buf * 32768 + L), 16, 0, 0);
    }
  };
  auto RD_A1 = [&](int p) {
#pragma unroll
    for (int m = 0; m < 4; ++m)
#pragma unroll
      for (int kk = 0; kk < 2; ++kk) a1[p][m][kk] = ldA(p, 1, m, kk);
  };
  auto RD_B1 = [&](int p) {
#pragma unroll
    for (int n = 0; n < 2; ++n)
#pragma unroll
      for (int kk = 0; kk < 2; ++kk) b1[p][n][kk] = ldB(p, 1, n, kk);
  };
  auto RD_A0B0 = [&](int p) {
#pragma unroll
    for (int m = 0; m < 4; ++m)
#pragma unroll
      for (int kk = 0; kk < 2; ++kk) a0[p][m][kk] = ldA(p, 0, m, kk);
#pragma unroll
    for (int n = 0; n < 2; ++n)
#pragma unroll
      for (int kk = 0; kk < 2; ++kk) b0[p][n][kk] = ldB(p, 0, n, kk);
  };
  auto Q1 = [&](int p) {
    __builtin_amdgcn_s_setprio(1);
#pragma unroll
    for (int m = 0; m < 4; ++m)
#pragma unroll
      for (int n = 0; n < 2; ++n)
#pragma unroll
        for (int kk = 0; kk < 2; ++kk)
          acc[m][n] = __builtin_amdgcn_mfma_f32_16x16x32_bf16(
              a0[p][m][kk], b0[p][n][kk], acc[m][n], 0, 0, 0);
    __builtin_amdgcn_s_setprio(0);
  };
  auto Q2 = [&](int p) {
    __builtin_amdgcn_s_setprio(1);
#pragma unroll
    for (int m = 0; m < 4; ++m)
#pragma unroll
      for (int n = 0; n < 2; ++n)
#pragma unroll
        for (int kk = 0; kk < 2; ++kk)
          acc[4 + m][n] = __builtin_amdgcn_mfma_f32_16x16x32_bf16(
              a1[p][m][kk], b0[p][n][kk], acc[4 + m][n], 0, 0, 0);
    __builtin_amdgcn_s_setprio(0);
  };
  auto Q3 = [&](int p) {
    __builtin_amdgcn_s_setprio(1);
#pragma unroll
    for (int m = 0; m < 4; ++m)
#pragma unroll
      for (int n = 0; n < 2; ++n)
#pragma unroll
        for (int kk = 0; kk < 2; ++kk)
          acc[4 + m][2 + n] = __builtin_amdgcn_mfma_f32_16x16x32_bf16(
              a1[p][m][kk], b1[p][n][kk], acc[4 + m][2 + n], 0, 0, 0);
    __builtin_amdgcn_s_setprio(0);
  };
  auto Q4 = [&](int p) {
    __builtin_amdgcn_s_setprio(1);
#pragma unroll
    for (int m = 0; m < 4; ++m)
#pragma unroll
      for (int n = 0; n < 2; ++n)
#pragma unroll
        for (int kk = 0; kk < 2; ++kk)
          acc[m][2 + n] = __builtin_amdgcn_mfma_f32_16x16x32_bf16(
              a0[p][m][kk], b1[p][n][kk], acc[m][2 + n], 0, 0, 0);
    __builtin_amdgcn_s_setprio(0);
  };
  auto flush = [&](int bc) {
    float bv[4];
#pragma unroll
    for (int n = 0; n < 4; ++n)
      bv[n] = bias[bc + (n >> 1) * 128 + wc * 32 + (n & 1) * 16 + fr];
#pragma unroll
    for (int m = 0; m < 8; ++m) {
      int grow0 = brow + (m >> 2) * 128 + wr * 64 + (m & 3) * 16 + slot * 4;
#pragma unroll
      for (int n = 0; n < 4; ++n) {
        int gcol = bc + (n >> 1) * 128 + wc * 32 + (n & 1) * 16 + fr;
#pragma unroll
        for (int r = 0; r < 4; ++r)
          C[(size_t)(grow0 + r) * GN + gcol] = acc[m][n][r] + bv[n];
      }
    }
  };
  auto iter = [&](int j) {
    int t1 = 2 * j + 1;
    int t2 = 2 * j + 2; if (t2 > NV - 1) t2 = NV - 1;  // tail dummy restage
    int t3 = 2 * j + 3; if (t3 > NV - 1) t3 = NV - 1;
    const unsigned short* B1p = (t1 < 32) ? Bbase0 : Bbase1;
    const unsigned short* B2p = (t2 < 32) ? Bbase0 : Bbase1;
    const unsigned short* B3p = (t3 < 32) ? Bbase0 : Bbase1;
    int kt1 = (t1 & 31) * BK, kt2 = (t2 & 31) * BK, kt3 = (t3 & 31) * BK;
    // P1
    RD_A1(0);
    stage(B1p, Bs, 1, 1, kt1);
    BAR();
    Q1(0);
    // P2
    RD_B1(0);
    BAR();
    Q2(0);
    // P3
    stage(Abase, As, 0, 0, kt2);
    stage(B2p, Bs, 0, 0, kt2);
    BAR();
    Q3(0);
    // P4
    stage(Abase, As, 0, 1, kt2);
    VM6();
    BAR();
    RD_A0B0(1);
    Q4(0);
    // P5
    RD_A1(1);
    stage(B2p, Bs, 0, 1, kt2);
    BAR();
    Q1(1);
    // P6
    RD_B1(1);
    BAR();
    Q2(1);
    // P7
    stage(Abase, As, 1, 0, kt3);
    stage(B3p, Bs, 1, 0, kt3);
    BAR();
    Q3(1);
    // P8
    stage(Abase, As, 1, 1, kt3);
    VM6();
    BAR();
    RD_A0B0(0);
    Q4(1);
  };

  // Prologue: stage v0 fully + v1 {A0,B0,A1}
  stage(Abase, As, 0, 0, 0);
  stage(Bbase0, Bs, 0, 0, 0);
  stage(Abase, As, 0, 1, 0);
  stage(Bbase0, Bs, 0, 1, 0);
  stage(Abase, As, 1, 0, BK);
  stage(Bbase0, Bs, 1, 0, BK);
  stage(Abase, As, 1, 1, BK);
  VM6();
  BAR();
  RD_A0B0(0);

#pragma unroll 1
  for (int j = 0; j < 16; ++j) iter(j);

  // mid-flush: tile-1 stores fly while tile-2's K-loop runs
  flush(bcol0);
#pragma unroll
  for (int m = 0; m < 8; ++m)
#pragma unroll
    for (int n = 0; n < 4; ++n)
      acc[m][n] = f32x4{0.f, 0.f, 0.f, 0.f};

#pragma unroll 1
  for (int j = 16; j < 32; ++j) iter(j);

  flush(bcol0 + 256);
}

// ---------------- Fallback (ws too small): fp32, correct, slow ----------------
__global__ void __launch_bounds__(256) fallback_kernel(
    const float* __restrict__ x, const int* __restrict__ q,
    const float* __restrict__ scale, const float* __restrict__ bias,
    float* __restrict__ out) {
  __shared__ float wrow[GK];
  int n = blockIdx.x;
  for (int k = threadIdx.x; k < GK; k += 256) {
    size_t idx = (size_t)n * GK + k;
    wrow[k] = NF4_LUT[q[idx] & 15] * scale[idx >> 6];
  }
  __syncthreads();
  int m = blockIdx.y * 256 + threadIdx.x;
  const float* xr = x + (size_t)m * GK;
  float acc = 0.f;
  for (int k = 0; k < GK; ++k) acc += xr[k] * wrow[k];
  out[(size_t)m * GN + n] = acc + bias[n];
}

extern "C" void kernel_launch(void* const* d_in, const int* in_sizes, int n_in,
                              void* d_out, int out_size, void* d_ws, size_t ws_size,
                              hipStream_t stream) {
  const float* x = (const float*)d_in[0];
  const int* q = (const int*)d_in[1];
  const float* scale = (const float*)d_in[2];
  const float* bias = (const float*)d_in[3];
  float* out = (float*)d_out;

  const size_t wbytes = (size_t)GN * GK * 2;
  const size_t xbytes = (size_t)GM * GK * 2;

  if (ws_size >= wbytes + xbytes) {
    unsigned short* wq = (unsigned short*)d_ws;
    unsigned short* xb = (unsigned short*)((char*)d_ws + wbytes);
    prep_kernel<<<dim3(8192 + 4096), 256, 0, stream>>>(q, scale, wq, x, xb);
    gemm_8phase_kernel<<<dim3(256), 512, 0, stream>>>(xb, wq, bias, out);
  } else {
    fallback_kernel<<<dim3(GN, GM / 256), 256, 0, stream>>>(x, q, scale, bias, out);
  }
}